// Round 2
// 621.535 us; speedup vs baseline: 1.0025x; 1.0025x over previous
//
#include <hip/hip_runtime.h>

#define VR_EPS 1e-10f
#define VR_S 128  // samples per ray (reference fixes n_samples=128)

// One 64-lane wave per ray; 2 samples per lane for the scan phase.
// rgb phase: fully-coalesced dwordx4 loads + LDS-staged weights
// (previous version: 3x dwordx2 at 24B inter-lane stride = 3x TA transactions).
__global__ __launch_bounds__(256) void vr_kernel(
    const float* __restrict__ alpha,   // [R, 128]
    const float* __restrict__ rgbs,    // [R, 128, 3]
    float* __restrict__ out_rgb,       // [R, 3]
    float* __restrict__ out_w,         // [R, 128]
    int n_rays)
{
    __shared__ float s_w[4][VR_S];     // 2 KB/block: per-wave weight staging

    const int wib     = threadIdx.x >> 6;   // wave index in block (0..3)
    const int lane    = threadIdx.x & 63;
    const int wave_id = blockIdx.x * 4 + wib;
    if (wave_id >= n_rays) return;
    const size_t ray = (size_t)wave_id;

    // ---- load 2 alphas per lane (coalesced float2 across the wave) ----
    const float2 a2 = *(const float2*)(alpha + ray * VR_S + 2 * lane);
    const float t0 = 1.0f - a2.x + VR_EPS;
    const float t1 = 1.0f - a2.y + VR_EPS;

    // ---- inclusive product-scan across 64 lanes (unchanged numerics) ----
    float inc = t0 * t1;
    #pragma unroll
    for (int off = 1; off < 64; off <<= 1) {
        float up = __shfl_up(inc, off, 64);
        inc *= (lane >= off) ? up : 1.0f;
    }
    // exclusive prefix (product of all lanes < this lane)
    float exc = __shfl_up(inc, 1, 64);
    if (lane == 0) exc = 1.0f;

    // trans for sample 2*lane is exc; for 2*lane+1 it's exc*t0
    const float w0 = exc * a2.x;
    const float w1 = exc * t0 * a2.y;

    // ---- weights: global (coalesced float2) + LDS stage for rgb phase ----
    *(float2*)(out_w + ray * VR_S + 2 * lane) = make_float2(w0, w1);
    *(float2*)(&s_w[wib][2 * lane]) = make_float2(w0, w1);
    // same wave produces and consumes s_w: compiler's lgkmcnt wait suffices,
    // no __syncthreads needed.

    // ---- rgb accumulation: 96 float4 per ray, fully coalesced ----
    const float* rp = rgbs + ray * (VR_S * 3);
    const float* wrow = s_w[wib];
    float r = 0.f, g = 0.f, b = 0.f;

    // float4 #k covers floats 4k..4k+3 -> exactly samples s0, s0+1
    // with leading channel c0 = (4k) % 3.
    {   // k = lane  (floats 0..255)
        const float4 v = *(const float4*)(rp + 4 * lane);
        const int f0 = 4 * lane;
        const int s0 = f0 / 3;
        const int c0 = f0 - 3 * s0;
        const float wa = wrow[s0];
        const float wb = wrow[s0 + 1];
        if (c0 == 0)      { r = fmaf(wa, v.x, r); g = fmaf(wa, v.y, g); b = fmaf(wa, v.z, b); r = fmaf(wb, v.w, r); }
        else if (c0 == 1) { g = fmaf(wa, v.x, g); b = fmaf(wa, v.y, b); r = fmaf(wb, v.z, r); g = fmaf(wb, v.w, g); }
        else              { b = fmaf(wa, v.x, b); r = fmaf(wb, v.y, r); g = fmaf(wb, v.z, g); b = fmaf(wb, v.w, b); }
    }
    if (lane < 32) {   // k = 64 + lane  (floats 256..383), half-wave
        const float4 v = *(const float4*)(rp + 4 * (64 + lane));
        const int f0 = 4 * (64 + lane);
        const int s0 = f0 / 3;
        const int c0 = f0 - 3 * s0;
        const float wa = wrow[s0];
        const float wb = wrow[s0 + 1];
        if (c0 == 0)      { r = fmaf(wa, v.x, r); g = fmaf(wa, v.y, g); b = fmaf(wa, v.z, b); r = fmaf(wb, v.w, r); }
        else if (c0 == 1) { g = fmaf(wa, v.x, g); b = fmaf(wa, v.y, b); r = fmaf(wb, v.z, r); g = fmaf(wb, v.w, g); }
        else              { b = fmaf(wa, v.x, b); r = fmaf(wb, v.y, r); g = fmaf(wb, v.z, g); b = fmaf(wb, v.w, b); }
    }

    // ---- wave reduction (xor butterfly: every lane ends with the full sum) ----
    #pragma unroll
    for (int m = 32; m > 0; m >>= 1) {
        r += __shfl_xor(r, m, 64);
        g += __shfl_xor(g, m, 64);
        b += __shfl_xor(b, m, 64);
    }
    if (lane < 3) {
        const float outv = (lane == 0) ? r : (lane == 1) ? g : b;
        out_rgb[ray * 3 + lane] = outv;   // one store instr, 3 active lanes
    }
}

extern "C" void kernel_launch(void* const* d_in, const int* in_sizes, int n_in,
                              void* d_out, int out_size, void* d_ws, size_t ws_size,
                              hipStream_t stream) {
    const float* alpha = (const float*)d_in[0];
    const float* rgbs  = (const float*)d_in[1];
    const int n_rays = in_sizes[0] / VR_S;

    float* out_rgb = (float*)d_out;                       // first R*3 floats
    float* out_w   = (float*)d_out + (size_t)n_rays * 3;  // then R*128 floats

    // 4 rays per 256-thread block (one wave each)
    const int blocks = (n_rays + 3) / 4;
    vr_kernel<<<blocks, 256, 0, stream>>>(alpha, rgbs, out_rgb, out_w, n_rays);
}